// Round 2
// baseline (11304.413 us; speedup 1.0000x reference)
//
#include <hip/hip_runtime.h>
#include <hip/hip_bf16.h>

typedef unsigned short ushort_t;

#define N_NODES 20000
#define N_EDGES 320000
#define F_NODE 64
#define F_EDGE 16
#define HID 300
#define DEPTH 3
#define N_GRAPHS 128

__device__ __forceinline__ float bf2f(ushort_t u) {
    union { unsigned int i; float f; } v;
    v.i = ((unsigned int)u) << 16;
    return v.f;
}
__device__ __forceinline__ ushort_t f2bf(float f) {
    union { float f; unsigned int i; } v;
    v.f = f;
    unsigned int x = v.i;
    unsigned int r = x + 0x7fffu + ((x >> 16) & 1u);  // RNE
    return (ushort_t)(r >> 16);
}

// K1: xW1[n][c] = b_init[c] + sum_k x[n][k] * W_init[k][c]   (k < 64)
__global__ __launch_bounds__(256) void node_init_gemm(
    const float* __restrict__ x, const float* __restrict__ W_init,
    const float* __restrict__ b_init, float* __restrict__ xW1)
{
    __shared__ float xs[16 * 64];
    const int tid = threadIdx.x;
    const long n0 = (long)blockIdx.x * 16;
    for (int i = tid; i < 16 * 64; i += 256) xs[i] = x[n0 * 64 + i];
    __syncthreads();
    const int nl = tid >> 4, ct = tid & 15;
    for (int q = 0; q < 19; ++q) {
        int c = ct + 16 * q;
        if (c < HID) {
            float acc = b_init[c];
            #pragma unroll 8
            for (int k = 0; k < 64; ++k)
                acc = fmaf(xs[nl * 64 + k], W_init[(long)k * HID + c], acc);
            xW1[(n0 + nl) * HID + c] = acc;
        }
    }
}

// K2: h[e][c] = relu(xW1[row[e]][c] + sum_{k<16} edge_attr[e][k]*W2[k][c])
// (h0 is NOT stored; it is recomputed in edge_update_tiled)
__global__ __launch_bounds__(256) void h0_init(
    const float* __restrict__ edge_attr, const int* __restrict__ row,
    const float* __restrict__ xW1, const float* __restrict__ W_init,
    ushort_t* __restrict__ h)
{
    __shared__ float W2s[16 * HID];
    __shared__ float eas[16 * 16];
    const int tid = threadIdx.x;
    const long e0 = (long)blockIdx.x * 16;
    for (int i = tid; i < 16 * HID; i += 256) {
        int k = i / HID, c = i % HID;
        W2s[i] = W_init[(long)(64 + k) * HID + c];
    }
    eas[tid] = edge_attr[e0 * 16 + tid];
    __syncthreads();
    const int el = tid >> 4, ct = tid & 15;
    const long e = e0 + el;
    const int r = row[e];
    float ea[16];
    #pragma unroll
    for (int k = 0; k < 16; ++k) ea[k] = eas[el * 16 + k];
    for (int q = 0; q < 19; ++q) {
        int c = ct + 16 * q;
        if (c < HID) {
            float acc = xW1[(long)r * HID + c];
            #pragma unroll
            for (int k = 0; k < 16; ++k)
                acc = fmaf(ea[k], W2s[k * HID + c], acc);
            acc = fmaxf(acc, 0.f);
            h[e * HID + c] = f2bf(acc);
        }
    }
}

// K3: IN-PLACE  h <- h @ W  (E x 300 @ 300 x 300), bf16 in/out, fp32 accumulate.
// Safe in-place: each output row e depends only on input row e, and the whole
// 64-row A-tile is staged to LDS before any global store. No __restrict__ on
// A/C since they alias.
__global__ __launch_bounds__(256) void gemm_ew(
    const ushort_t* A, const float* __restrict__ W, ushort_t* Cb)
{
    __shared__ ushort_t At[300 * 68];   // transposed A tile, pad 68
    __shared__ float Ws[32 * 128];
    const int tid = threadIdx.x;
    const long e0 = (long)blockIdx.x * 64;

    for (int i = tid; i < 64 * 75; i += 256) {
        int e = i / 75, g = i % 75;
        const ushort4 v = *(((const ushort4*)A) + ((e0 + e) * 75 + g));
        int k = 4 * g;
        At[(k + 0) * 68 + e] = v.x;
        At[(k + 1) * 68 + e] = v.y;
        At[(k + 2) * 68 + e] = v.z;
        At[(k + 3) * 68 + e] = v.w;
    }
    __syncthreads();

    const int et = tid >> 4;  // 0..15 -> 4 edges each
    const int ct = tid & 15;  // 0..15 -> 8 cols each

    for (int cc = 0; cc < 3; ++cc) {
        const int c0 = cc * 128;
        float acc[4][8];
        #pragma unroll
        for (int i = 0; i < 4; ++i)
            #pragma unroll
            for (int j = 0; j < 8; ++j) acc[i][j] = 0.f;

        for (int k0 = 0; k0 < HID; k0 += 32) {
            const int klen = (HID - k0 < 32) ? (HID - k0) : 32;
            {
                int r = tid >> 3;
                int cg = (tid & 7) * 16;
                if (r < klen) {
                    if (c0 + 128 <= HID) {
                        const float4* src = (const float4*)&W[(long)(k0 + r) * HID + c0 + cg];
                        float4 a0 = src[0], a1 = src[1], a2 = src[2], a3 = src[3];
                        float4* dst = (float4*)&Ws[r * 128 + cg];
                        dst[0] = a0; dst[1] = a1; dst[2] = a2; dst[3] = a3;
                    } else {
                        for (int j = 0; j < 16; ++j) {
                            int c = c0 + cg + j;
                            Ws[r * 128 + cg + j] = (c < HID) ? W[(long)(k0 + r) * HID + c] : 0.f;
                        }
                    }
                }
            }
            __syncthreads();
            #pragma unroll 4
            for (int kk = 0; kk < klen; ++kk) {
                ushort4 av = *(const ushort4*)&At[(k0 + kk) * 68 + 4 * et];
                float avv[4] = {bf2f(av.x), bf2f(av.y), bf2f(av.z), bf2f(av.w)};
                const float4 w0 = *(const float4*)&Ws[kk * 128 + 8 * ct];
                const float4 w1 = *(const float4*)&Ws[kk * 128 + 8 * ct + 4];
                float wv[8] = {w0.x, w0.y, w0.z, w0.w, w1.x, w1.y, w1.z, w1.w};
                #pragma unroll
                for (int i = 0; i < 4; ++i)
                    #pragma unroll
                    for (int j = 0; j < 8; ++j)
                        acc[i][j] = fmaf(avv[i], wv[j], acc[i][j]);
            }
            __syncthreads();
        }
        #pragma unroll
        for (int i = 0; i < 4; ++i) {
            long e = e0 + 4 * et + i;
            #pragma unroll
            for (int j = 0; j < 8; ++j) {
                int c = c0 + 8 * ct + j;
                if (c < HID) Cb[e * HID + c] = f2bf(acc[i][j]);
            }
        }
    }
}

// K4: S[col[e]][:] += src[e][:]   (fp32 atomics, src bf16)
__global__ __launch_bounds__(256) void scatter_add(
    const ushort_t* __restrict__ src, const int* __restrict__ col,
    float* __restrict__ S)
{
    long idx = (long)blockIdx.x * 256 + threadIdx.x;  // < E*75
    long e = idx / 75;
    int g = (int)(idx % 75);
    ushort4 v = *(((const ushort4*)src) + e * 75 + g);
    int n = col[e];
    float* dst = &S[(long)n * HID + 4 * g];
    atomicAdd(dst + 0, bf2f(v.x));
    atomicAdd(dst + 1, bf2f(v.y));
    atomicAdd(dst + 2, bf2f(v.z));
    atomicAdd(dst + 3, bf2f(v.w));
}

// K5: tiled IN-PLACE edge update over 64-edge tiles (pairs 2i,2i+1 never cross
// a 64-edge tile).  h currently holds hW = h_prev @ W.
//   h_new[e] = relu(S[row[e]] - hW[e^1] + bias + h0[e]),
//   h0[e] recomputed = relu(xW1[row[e]] + edge_attr[e] @ W2)
__global__ __launch_bounds__(256) void edge_update_tiled(
    ushort_t* h, const float* __restrict__ S,
    const float* __restrict__ xW1, const float* __restrict__ edge_attr,
    const float* __restrict__ W2,   // = W_init + 64*HID, [16][HID]
    const float* __restrict__ bias, const int* __restrict__ row)
{
    __shared__ ushort_t hWs[64 * 300];  // 38.4 KB
    __shared__ float eas[64 * 16];      // 4 KB
    __shared__ int rows[64];
    const int tid = threadIdx.x;
    const long e0 = (long)blockIdx.x * 64;

    for (int i = tid; i < 64 * 75; i += 256)
        ((ushort4*)hWs)[i] = ((const ushort4*)h)[e0 * 75 + i];
    for (int i = tid; i < 64 * 16; i += 256)
        eas[i] = edge_attr[e0 * 16 + i];
    if (tid < 64) rows[tid] = row[e0 + tid];
    __syncthreads();

    for (int i = tid; i < 64 * 75; i += 256) {
        int e = i / 75, g = i % 75;
        int c0 = 4 * g;
        long E = e0 + e;
        int r = rows[e];
        ushort4 wv = *(const ushort4*)&hWs[(e ^ 1) * 300 + c0];
        float4 sv = *(const float4*)&S[(long)r * HID + c0];
        float4 bv = *(const float4*)&bias[c0];
        float4 xv = *(const float4*)&xW1[(long)r * HID + c0];
        float h0r[4] = {xv.x, xv.y, xv.z, xv.w};
        #pragma unroll
        for (int k = 0; k < 16; ++k) {
            float a = eas[e * 16 + k];
            const float4 w = *(const float4*)&W2[(long)k * HID + c0];
            h0r[0] = fmaf(a, w.x, h0r[0]);
            h0r[1] = fmaf(a, w.y, h0r[1]);
            h0r[2] = fmaf(a, w.z, h0r[2]);
            h0r[3] = fmaf(a, w.w, h0r[3]);
        }
        float o0 = fmaxf(sv.x - bf2f(wv.x) + bv.x + fmaxf(h0r[0], 0.f), 0.f);
        float o1 = fmaxf(sv.y - bf2f(wv.y) + bv.y + fmaxf(h0r[1], 0.f), 0.f);
        float o2 = fmaxf(sv.z - bf2f(wv.z) + bv.z + fmaxf(h0r[2], 0.f), 0.f);
        float o3 = fmaxf(sv.w - bf2f(wv.w) + bv.w + fmaxf(h0r[3], 0.f), 0.f);
        ushort4 ov;
        ov.x = f2bf(o0); ov.y = f2bf(o1); ov.z = f2bf(o2); ov.w = f2bf(o3);
        ((ushort4*)h)[E * 75 + g] = ov;
    }
}

// K7: hn[n] = relu(cat(x[n],S[n]) @ W_e2n + b); atomic pool into pooled[batch[n]]
__global__ __launch_bounds__(256) void e2n_pool(
    const float* __restrict__ x, const float* __restrict__ S,
    const float* __restrict__ W, const float* __restrict__ b,
    const int* __restrict__ batch, float* __restrict__ pooled)
{
    __shared__ float xs[16 * 64];
    __shared__ float Ss[16 * HID];
    const int tid = threadIdx.x;
    const long n0 = (long)blockIdx.x * 16;
    for (int i = tid; i < 16 * 64; i += 256) xs[i] = x[n0 * 64 + i];
    for (int i = tid; i < 16 * HID; i += 256) Ss[i] = S[n0 * HID + i];
    __syncthreads();
    const int nl = tid >> 4, ct = tid & 15;
    const long n = n0 + nl;
    const int gidx = batch[n];
    for (int q = 0; q < 19; ++q) {
        int c = ct + 16 * q;
        if (c < HID) {
            float acc = b[c];
            #pragma unroll 8
            for (int k = 0; k < 64; ++k)
                acc = fmaf(xs[nl * 64 + k], W[(long)k * HID + c], acc);
            #pragma unroll 4
            for (int k = 0; k < HID; ++k)
                acc = fmaf(Ss[nl * HID + k], W[(long)(64 + k) * HID + c], acc);
            acc = fmaxf(acc, 0.f);
            atomicAdd(&pooled[(long)gidx * HID + c], acc);
        }
    }
}

// K8: out[g] = pooled[g] @ W_ffn + b_ffn
__global__ __launch_bounds__(64) void ffn_out(
    const float* __restrict__ pooled, const float* __restrict__ W_ffn,
    const float* __restrict__ b_ffn, float* __restrict__ out)
{
    int g = blockIdx.x;
    int lane = threadIdx.x;
    float s = 0.f;
    for (int c = lane; c < HID; c += 64)
        s += pooled[(long)g * HID + c] * W_ffn[c];
    #pragma unroll
    for (int off = 32; off > 0; off >>= 1)
        s += __shfl_down(s, off, 64);
    if (lane == 0) out[g] = s + b_ffn[0];
}

extern "C" void kernel_launch(void* const* d_in, const int* in_sizes, int n_in,
                              void* d_out, int out_size, void* d_ws, size_t ws_size,
                              hipStream_t stream) {
    const float* x         = (const float*)d_in[0];
    const float* edge_attr = (const float*)d_in[1];
    const int*   edge_index= (const int*)d_in[2];
    const int*   batch     = (const int*)d_in[3];
    const float* W_init    = (const float*)d_in[4];
    const float* b_init    = (const float*)d_in[5];
    const float* W_convs   = (const float*)d_in[6];
    const float* b_convs   = (const float*)d_in[7];
    const float* W_e2n     = (const float*)d_in[8];
    const float* b_e2n     = (const float*)d_in[9];
    const float* W_ffn     = (const float*)d_in[10];
    const float* b_ffn     = (const float*)d_in[11];
    float* out = (float*)d_out;

    const int* row = edge_index;
    const int* col = edge_index + N_EDGES;
    const float* W2 = W_init + (size_t)F_NODE * HID;

    // Workspace plan (240,153,600 bytes total):
    //   h:    E*300 bf16 = 192,000,000
    //   S:    N*300 f32  =  24,000,000
    //   xW1:  N*300 f32  =  24,000,000
    //   pooled: G*300 f32 =    153,600
    const size_t need = (size_t)N_EDGES * HID * 2 + (size_t)N_NODES * HID * 4 * 2
                      + (size_t)N_GRAPHS * HID * 4;
    if (ws_size < need) return;  // diagnostic guard: clean absmax fail, not a crash

    char* p = (char*)d_ws;
    auto take = [&](size_t bytes) {
        char* q = p;
        p += (bytes + 255) & ~(size_t)255;
        return q;
    };
    ushort_t* h      = (ushort_t*)take((size_t)N_EDGES * HID * 2);
    float*    S      = (float*)take((size_t)N_NODES * HID * 4);
    float*    xW1    = (float*)take((size_t)N_NODES * HID * 4);
    float*    pooled = (float*)take((size_t)N_GRAPHS * HID * 4);

    node_init_gemm<<<N_NODES / 16, 256, 0, stream>>>(x, W_init, b_init, xW1);
    h0_init<<<N_EDGES / 16, 256, 0, stream>>>(edge_attr, row, xW1, W_init, h);

    for (int l = 0; l < DEPTH; ++l) {
        gemm_ew<<<N_EDGES / 64, 256, 0, stream>>>(h, W_convs + (size_t)l * HID * HID, h);
        hipMemsetAsync(S, 0, (size_t)N_NODES * HID * 4, stream);
        scatter_add<<<(N_EDGES * 75) / 256, 256, 0, stream>>>(h, col, S);
        edge_update_tiled<<<N_EDGES / 64, 256, 0, stream>>>(
            h, S, xW1, edge_attr, W2, b_convs + l * HID, row);
    }

    hipMemsetAsync(S, 0, (size_t)N_NODES * HID * 4, stream);
    scatter_add<<<(N_EDGES * 75) / 256, 256, 0, stream>>>(h, col, S);
    hipMemsetAsync(pooled, 0, (size_t)N_GRAPHS * HID * 4, stream);
    e2n_pool<<<N_NODES / 16, 256, 0, stream>>>(x, S, W_e2n, b_e2n, batch, pooled);
    ffn_out<<<N_GRAPHS, 64, 0, stream>>>(pooled, W_ffn, b_ffn, out);
}

// Round 3
// 5822.105 us; speedup vs baseline: 1.9416x; 1.9416x over previous
//
#include <hip/hip_runtime.h>
#include <hip/hip_bf16.h>

typedef unsigned short ushort_t;

#define N_NODES 20000
#define N_EDGES 320000
#define F_NODE 64
#define F_EDGE 16
#define HID 300
#define DEPTH 3
#define N_GRAPHS 128

__device__ __forceinline__ float bf2f(ushort_t u) {
    union { unsigned int i; float f; } v;
    v.i = ((unsigned int)u) << 16;
    return v.f;
}
__device__ __forceinline__ ushort_t f2bf(float f) {
    union { float f; unsigned int i; } v;
    v.f = f;
    unsigned int x = v.i;
    unsigned int r = x + 0x7fffu + ((x >> 16) & 1u);  // RNE
    return (ushort_t)(r >> 16);
}

// ---------------- CSR build (col -> node adjacency) ----------------
__global__ __launch_bounds__(256) void csr_hist(
    const int* __restrict__ col, int* __restrict__ deg)
{
    int e = blockIdx.x * 256 + threadIdx.x;
    atomicAdd(&deg[col[e]], 1);
}

// single-block exclusive scan of deg[20000] -> offsets, cursor
__global__ __launch_bounds__(256) void csr_scan(
    const int* __restrict__ deg, int* __restrict__ offsets,
    int* __restrict__ cursor)
{
    __shared__ int sums[256];
    const int t = threadIdx.x;
    const int CH = 79;  // 256*79 = 20224 >= 20000
    int base = t * CH;
    int local = 0;
    for (int i = 0; i < CH; ++i) {
        int idx = base + i;
        if (idx < N_NODES) local += deg[idx];
    }
    sums[t] = local;
    __syncthreads();
    for (int off = 1; off < 256; off <<= 1) {
        int v = (t >= off) ? sums[t - off] : 0;
        __syncthreads();
        sums[t] += v;
        __syncthreads();
    }
    int run = (t > 0) ? sums[t - 1] : 0;
    for (int i = 0; i < CH; ++i) {
        int idx = base + i;
        if (idx < N_NODES) {
            offsets[idx] = run;
            cursor[idx] = run;
            run += deg[idx];
        }
    }
}

__global__ __launch_bounds__(256) void csr_fill(
    const int* __restrict__ col, int* __restrict__ cursor,
    int* __restrict__ eid)
{
    int e = blockIdx.x * 256 + threadIdx.x;
    int pos = atomicAdd(&cursor[col[e]], 1);
    eid[pos] = e;
}

// ---------------- kernels ----------------

// K1: xW1[n][c] = b_init[c] + sum_k x[n][k] * W_init[k][c]   (k < 64)
__global__ __launch_bounds__(256) void node_init_gemm(
    const float* __restrict__ x, const float* __restrict__ W_init,
    const float* __restrict__ b_init, float* __restrict__ xW1)
{
    __shared__ float xs[16 * 64];
    const int tid = threadIdx.x;
    const long n0 = (long)blockIdx.x * 16;
    for (int i = tid; i < 16 * 64; i += 256) xs[i] = x[n0 * 64 + i];
    __syncthreads();
    const int nl = tid >> 4, ct = tid & 15;
    for (int q = 0; q < 19; ++q) {
        int c = ct + 16 * q;
        if (c < HID) {
            float acc = b_init[c];
            #pragma unroll 8
            for (int k = 0; k < 64; ++k)
                acc = fmaf(xs[nl * 64 + k], W_init[(long)k * HID + c], acc);
            xW1[(n0 + nl) * HID + c] = acc;
        }
    }
}

// K2: h[e][c] = relu(xW1[row[e]][c] + sum_{k<16} edge_attr[e][k]*W2[k][c])
__global__ __launch_bounds__(256) void h0_init(
    const float* __restrict__ edge_attr, const int* __restrict__ row,
    const float* __restrict__ xW1, const float* __restrict__ W_init,
    ushort_t* __restrict__ h)
{
    __shared__ float W2s[16 * HID];
    __shared__ float eas[16 * 16];
    const int tid = threadIdx.x;
    const long e0 = (long)blockIdx.x * 16;
    for (int i = tid; i < 16 * HID; i += 256) {
        int k = i / HID, c = i % HID;
        W2s[i] = W_init[(long)(64 + k) * HID + c];
    }
    eas[tid] = edge_attr[e0 * 16 + tid];
    __syncthreads();
    const int el = tid >> 4, ct = tid & 15;
    const long e = e0 + el;
    const int r = row[e];
    float ea[16];
    #pragma unroll
    for (int k = 0; k < 16; ++k) ea[k] = eas[el * 16 + k];
    for (int q = 0; q < 19; ++q) {
        int c = ct + 16 * q;
        if (c < HID) {
            float acc = xW1[(long)r * HID + c];
            #pragma unroll
            for (int k = 0; k < 16; ++k)
                acc = fmaf(ea[k], W2s[k * HID + c], acc);
            acc = fmaxf(acc, 0.f);
            h[e * HID + c] = f2bf(acc);
        }
    }
}

// K3: IN-PLACE  h <- h @ W  (E x 300 @ 300 x 300), bf16 in/out, fp32 accumulate.
__global__ __launch_bounds__(256) void gemm_ew(
    const ushort_t* A, const float* __restrict__ W, ushort_t* Cb)
{
    __shared__ ushort_t At[300 * 68];   // transposed A tile, pad 68
    __shared__ float Ws[32 * 128];
    const int tid = threadIdx.x;
    const long e0 = (long)blockIdx.x * 64;

    for (int i = tid; i < 64 * 75; i += 256) {
        int e = i / 75, g = i % 75;
        const ushort4 v = *(((const ushort4*)A) + ((e0 + e) * 75 + g));
        int k = 4 * g;
        At[(k + 0) * 68 + e] = v.x;
        At[(k + 1) * 68 + e] = v.y;
        At[(k + 2) * 68 + e] = v.z;
        At[(k + 3) * 68 + e] = v.w;
    }
    __syncthreads();

    const int et = tid >> 4;
    const int ct = tid & 15;

    for (int cc = 0; cc < 3; ++cc) {
        const int c0 = cc * 128;
        float acc[4][8];
        #pragma unroll
        for (int i = 0; i < 4; ++i)
            #pragma unroll
            for (int j = 0; j < 8; ++j) acc[i][j] = 0.f;

        for (int k0 = 0; k0 < HID; k0 += 32) {
            const int klen = (HID - k0 < 32) ? (HID - k0) : 32;
            {
                int r = tid >> 3;
                int cg = (tid & 7) * 16;
                if (r < klen) {
                    if (c0 + 128 <= HID) {
                        const float4* src = (const float4*)&W[(long)(k0 + r) * HID + c0 + cg];
                        float4 a0 = src[0], a1 = src[1], a2 = src[2], a3 = src[3];
                        float4* dst = (float4*)&Ws[r * 128 + cg];
                        dst[0] = a0; dst[1] = a1; dst[2] = a2; dst[3] = a3;
                    } else {
                        for (int j = 0; j < 16; ++j) {
                            int c = c0 + cg + j;
                            Ws[r * 128 + cg + j] = (c < HID) ? W[(long)(k0 + r) * HID + c] : 0.f;
                        }
                    }
                }
            }
            __syncthreads();
            #pragma unroll 4
            for (int kk = 0; kk < klen; ++kk) {
                ushort4 av = *(const ushort4*)&At[(k0 + kk) * 68 + 4 * et];
                float avv[4] = {bf2f(av.x), bf2f(av.y), bf2f(av.z), bf2f(av.w)};
                const float4 w0 = *(const float4*)&Ws[kk * 128 + 8 * ct];
                const float4 w1 = *(const float4*)&Ws[kk * 128 + 8 * ct + 4];
                float wv[8] = {w0.x, w0.y, w0.z, w0.w, w1.x, w1.y, w1.z, w1.w};
                #pragma unroll
                for (int i = 0; i < 4; ++i)
                    #pragma unroll
                    for (int j = 0; j < 8; ++j)
                        acc[i][j] = fmaf(avv[i], wv[j], acc[i][j]);
            }
            __syncthreads();
        }
        #pragma unroll
        for (int i = 0; i < 4; ++i) {
            long e = e0 + 4 * et + i;
            #pragma unroll
            for (int j = 0; j < 8; ++j) {
                int c = c0 + 8 * ct + j;
                if (c < HID) Cb[e * HID + c] = f2bf(acc[i][j]);
            }
        }
    }
}

// K4: S[n][:] = sum over CSR edges of src[eid][:]   (no atomics)
__global__ __launch_bounds__(256) void gather_sum(
    const ushort_t* __restrict__ src, const int* __restrict__ offsets,
    const int* __restrict__ ends, const int* __restrict__ eid,
    float* __restrict__ S)
{
    long idx = (long)blockIdx.x * 256 + threadIdx.x;
    if (idx >= (long)N_NODES * 75) return;
    int n = (int)(idx / 75);
    int g = (int)(idx % 75);
    int beg = offsets[n], end = ends[n];
    float a0 = 0.f, a1 = 0.f, a2 = 0.f, a3 = 0.f;
    for (int j = beg; j < end; ++j) {
        int e = eid[j];
        ushort4 v = ((const ushort4*)src)[(long)e * 75 + g];
        a0 += bf2f(v.x); a1 += bf2f(v.y); a2 += bf2f(v.z); a3 += bf2f(v.w);
    }
    float4 o = {a0, a1, a2, a3};
    *(float4*)&S[(long)n * HID + 4 * g] = o;
}

// K5: tiled IN-PLACE edge update (pairs 2i,2i+1 never cross a 64-edge tile)
__global__ __launch_bounds__(256) void edge_update_tiled(
    ushort_t* h, const float* __restrict__ S,
    const float* __restrict__ xW1, const float* __restrict__ edge_attr,
    const float* __restrict__ W2, const float* __restrict__ bias,
    const int* __restrict__ row)
{
    __shared__ ushort_t hWs[64 * 300];
    __shared__ float eas[64 * 16];
    __shared__ int rows[64];
    const int tid = threadIdx.x;
    const long e0 = (long)blockIdx.x * 64;

    for (int i = tid; i < 64 * 75; i += 256)
        ((ushort4*)hWs)[i] = ((const ushort4*)h)[e0 * 75 + i];
    for (int i = tid; i < 64 * 16; i += 256)
        eas[i] = edge_attr[e0 * 16 + i];
    if (tid < 64) rows[tid] = row[e0 + tid];
    __syncthreads();

    for (int i = tid; i < 64 * 75; i += 256) {
        int e = i / 75, g = i % 75;
        int c0 = 4 * g;
        long E = e0 + e;
        int r = rows[e];
        ushort4 wv = *(const ushort4*)&hWs[(e ^ 1) * 300 + c0];
        float4 sv = *(const float4*)&S[(long)r * HID + c0];
        float4 bv = *(const float4*)&bias[c0];
        float4 xv = *(const float4*)&xW1[(long)r * HID + c0];
        float h0r[4] = {xv.x, xv.y, xv.z, xv.w};
        #pragma unroll
        for (int k = 0; k < 16; ++k) {
            float a = eas[e * 16 + k];
            const float4 w = *(const float4*)&W2[(long)k * HID + c0];
            h0r[0] = fmaf(a, w.x, h0r[0]);
            h0r[1] = fmaf(a, w.y, h0r[1]);
            h0r[2] = fmaf(a, w.z, h0r[2]);
            h0r[3] = fmaf(a, w.w, h0r[3]);
        }
        float o0 = fmaxf(sv.x - bf2f(wv.x) + bv.x + fmaxf(h0r[0], 0.f), 0.f);
        float o1 = fmaxf(sv.y - bf2f(wv.y) + bv.y + fmaxf(h0r[1], 0.f), 0.f);
        float o2 = fmaxf(sv.z - bf2f(wv.z) + bv.z + fmaxf(h0r[2], 0.f), 0.f);
        float o3 = fmaxf(sv.w - bf2f(wv.w) + bv.w + fmaxf(h0r[3], 0.f), 0.f);
        ushort4 ov;
        ov.x = f2bf(o0); ov.y = f2bf(o1); ov.z = f2bf(o2); ov.w = f2bf(o3);
        ((ushort4*)h)[E * 75 + g] = ov;
    }
}

// K7: hn[n] = relu(cat(x[n],S[n]) @ W_e2n + b); atomic pool into pooled[batch[n]]
__global__ __launch_bounds__(256) void e2n_pool(
    const float* __restrict__ x, const float* __restrict__ S,
    const float* __restrict__ W, const float* __restrict__ b,
    const int* __restrict__ batch, float* __restrict__ pooled)
{
    __shared__ float xs[16 * 64];
    __shared__ float Ss[16 * HID];
    const int tid = threadIdx.x;
    const long n0 = (long)blockIdx.x * 16;
    for (int i = tid; i < 16 * 64; i += 256) xs[i] = x[n0 * 64 + i];
    for (int i = tid; i < 16 * HID; i += 256) Ss[i] = S[n0 * HID + i];
    __syncthreads();
    const int nl = tid >> 4, ct = tid & 15;
    const long n = n0 + nl;
    const int gidx = batch[n];
    for (int q = 0; q < 19; ++q) {
        int c = ct + 16 * q;
        if (c < HID) {
            float acc = b[c];
            #pragma unroll 8
            for (int k = 0; k < 64; ++k)
                acc = fmaf(xs[nl * 64 + k], W[(long)k * HID + c], acc);
            #pragma unroll 4
            for (int k = 0; k < HID; ++k)
                acc = fmaf(Ss[nl * HID + k], W[(long)(64 + k) * HID + c], acc);
            acc = fmaxf(acc, 0.f);
            atomicAdd(&pooled[(long)gidx * HID + c], acc);
        }
    }
}

// K8: out[g] = pooled[g] @ W_ffn + b_ffn
__global__ __launch_bounds__(64) void ffn_out(
    const float* __restrict__ pooled, const float* __restrict__ W_ffn,
    const float* __restrict__ b_ffn, float* __restrict__ out)
{
    int g = blockIdx.x;
    int lane = threadIdx.x;
    float s = 0.f;
    for (int c = lane; c < HID; c += 64)
        s += pooled[(long)g * HID + c] * W_ffn[c];
    #pragma unroll
    for (int off = 32; off > 0; off >>= 1)
        s += __shfl_down(s, off, 64);
    if (lane == 0) out[g] = s + b_ffn[0];
}

extern "C" void kernel_launch(void* const* d_in, const int* in_sizes, int n_in,
                              void* d_out, int out_size, void* d_ws, size_t ws_size,
                              hipStream_t stream) {
    const float* x         = (const float*)d_in[0];
    const float* edge_attr = (const float*)d_in[1];
    const int*   edge_index= (const int*)d_in[2];
    const int*   batch     = (const int*)d_in[3];
    const float* W_init    = (const float*)d_in[4];
    const float* b_init    = (const float*)d_in[5];
    const float* W_convs   = (const float*)d_in[6];
    const float* b_convs   = (const float*)d_in[7];
    const float* W_e2n     = (const float*)d_in[8];
    const float* b_e2n     = (const float*)d_in[9];
    const float* W_ffn     = (const float*)d_in[10];
    const float* b_ffn     = (const float*)d_in[11];
    float* out = (float*)d_out;

    const int* row = edge_index;
    const int* col = edge_index + N_EDGES;
    const float* W2 = W_init + (size_t)F_NODE * HID;

    // Workspace plan (~241.6 MB):
    //   h: 192 MB | S: 24 MB | xW1: 24 MB | pooled: 150 KB
    //   deg/cursor: 80 KB | offsets: 80 KB | eid: 1.28 MB
    const size_t need = (size_t)N_EDGES * HID * 2 + (size_t)N_NODES * HID * 4 * 2
                      + (size_t)N_GRAPHS * HID * 4 + (size_t)N_NODES * 4 * 2
                      + (size_t)N_EDGES * 4 + 4096;
    if (ws_size < need) return;  // clean absmax fail, not a crash

    char* p = (char*)d_ws;
    auto take = [&](size_t bytes) {
        char* q = p;
        p += (bytes + 255) & ~(size_t)255;
        return q;
    };
    ushort_t* h       = (ushort_t*)take((size_t)N_EDGES * HID * 2);
    float*    S       = (float*)take((size_t)N_NODES * HID * 4);
    float*    xW1     = (float*)take((size_t)N_NODES * HID * 4);
    float*    pooled  = (float*)take((size_t)N_GRAPHS * HID * 4);
    int*      cursor  = (int*)take((size_t)N_NODES * 4);   // deg, then fill cursor
    int*      offsets = (int*)take((size_t)N_NODES * 4);
    int*      eid     = (int*)take((size_t)N_EDGES * 4);

    // CSR build (col -> incoming edge list per node)
    hipMemsetAsync(cursor, 0, (size_t)N_NODES * 4, stream);
    csr_hist<<<N_EDGES / 256, 256, 0, stream>>>(col, cursor);
    csr_scan<<<1, 256, 0, stream>>>(cursor, offsets, cursor);  // reads deg, writes offsets+cursor
    // NOTE: csr_scan reads and rewrites `cursor` — safe because each element is
    // read before being overwritten by the same thread.
    csr_fill<<<N_EDGES / 256, 256, 0, stream>>>(col, cursor, eid);
    // after fill: cursor[n] == end offset of node n

    node_init_gemm<<<N_NODES / 16, 256, 0, stream>>>(x, W_init, b_init, xW1);
    h0_init<<<N_EDGES / 16, 256, 0, stream>>>(edge_attr, row, xW1, W_init, h);

    const int GS_GRID = ((N_NODES * 75) + 255) / 256;
    for (int l = 0; l < DEPTH; ++l) {
        gemm_ew<<<N_EDGES / 64, 256, 0, stream>>>(h, W_convs + (size_t)l * HID * HID, h);
        gather_sum<<<GS_GRID, 256, 0, stream>>>(h, offsets, cursor, eid, S);
        edge_update_tiled<<<N_EDGES / 64, 256, 0, stream>>>(
            h, S, xW1, edge_attr, W2, b_convs + l * HID, row);
    }

    gather_sum<<<GS_GRID, 256, 0, stream>>>(h, offsets, cursor, eid, S);
    hipMemsetAsync(pooled, 0, (size_t)N_GRAPHS * HID * 4, stream);
    e2n_pool<<<N_NODES / 16, 256, 0, stream>>>(x, S, W_e2n, b_e2n, batch, pooled);
    ffn_out<<<N_GRAPHS, 64, 0, stream>>>(pooled, W_ffn, b_ffn, out);
}